// Round 7
// baseline (835.254 us; speedup 1.0000x reference)
//
#include <hip/hip_runtime.h>

// multi_SelfAttention on MI355X (gfx950). Inputs fp32 (runtime-detected);
// bf16 MFMA compute; output dtype per flag.
// convert -> proj1 -> proj2 (Q pre-scaled 0.125*log2e) -> flash attn -> proj3.

typedef __bf16 bf16x8 __attribute__((ext_vector_type(8)));
typedef float floatx4 __attribute__((ext_vector_type(4)));

#define LDP 72  // padded stride for GEMM A tiles only

// Universal 64-stride tile swizzle: conflict-free for row-major b128 reads
// (row=..+ln) AND transpose-scatter b16 stores (bank-verified).
#define SW64(row, col) (((row) << 6) | (((((col) >> 3) ^ ((row) & 7) ^ (((row) >> 3) & 7)) << 3) | ((col) & 7)))
// Ps swizzle (r5-proven): store (row=quad*4+r, col=jt*16+ln) & read (row=..+ln) conflict-free
#define PSW(row, col) (((row) << 6) | (((((col) >> 3) ^ (((row) & 7) ^ ((((row) >> 3) & 1) << 1))) << 3) | ((col) & 7)))

#if __has_builtin(__builtin_amdgcn_exp2f)
__device__ __forceinline__ float fast_exp2(float x) { return __builtin_amdgcn_exp2f(x); }
#else
__device__ __forceinline__ float fast_exp2(float x) { return exp2f(x); }
#endif

template <int CTRL>
__device__ __forceinline__ float dpp_bcast(float x) {
    return __int_as_float(__builtin_amdgcn_update_dpp(0, __float_as_int(x), CTRL, 0xF, 0xF, false));
}
__device__ __forceinline__ float red16_max(float x) {
    x = fmaxf(x, dpp_bcast<0xB1>(x));   // quad_perm [1,0,3,2]
    x = fmaxf(x, dpp_bcast<0x4E>(x));   // quad_perm [2,3,0,1]
    x = fmaxf(x, dpp_bcast<0x141>(x));  // row_half_mirror
    x = fmaxf(x, dpp_bcast<0x140>(x));  // row_mirror
    return x;
}
__device__ __forceinline__ float red16_sum(float x) {
    x += dpp_bcast<0xB1>(x);
    x += dpp_bcast<0x4E>(x);
    x += dpp_bcast<0x141>(x);
    x += dpp_bcast<0x140>(x);
    return x;
}

// ---------------------------------------------------------------------------
__global__ void detect_dtype(const unsigned short* __restrict__ z, int* __restrict__ flag) {
    __shared__ int cnt;
    if (threadIdx.x == 0) cnt = 0;
    __syncthreads();
    int local = 0;
    for (int i = threadIdx.x; i < 16384; i += 256) {
        unsigned int u = (unsigned int)z[i] << 16;
        float x = __uint_as_float(u);
        float ax = fabsf(x);
        if (!(ax <= 1024.0f) || (x != 0.0f && ax < 1e-20f)) local++;
    }
    atomicAdd(&cnt, local);
    __syncthreads();
    if (threadIdx.x == 0) *flag = (cnt > 1310) ? 1 : 0;
}

// ---------------------------------------------------------------------------
struct ConvArgs { const void* src[12]; int n[12]; int off[12]; };

__global__ void convert_inputs(ConvArgs a, __bf16* __restrict__ cv, const int* __restrict__ flag,
                               int base_k) {
    const int k = blockIdx.y + base_k;
    const int i = (blockIdx.x * 256 + threadIdx.x) * 8;
    if (i >= a.n[k]) return;
    __bf16* dst = cv + a.off[k] + i;
    if (*flag) {
        const float* s = (const float*)a.src[k] + i;
        float4 f0 = *(const float4*)s;
        float4 f1 = *(const float4*)(s + 4);
        bf16x8 v;
        v[0] = (__bf16)f0.x; v[1] = (__bf16)f0.y; v[2] = (__bf16)f0.z; v[3] = (__bf16)f0.w;
        v[4] = (__bf16)f1.x; v[5] = (__bf16)f1.y; v[6] = (__bf16)f1.z; v[7] = (__bf16)f1.w;
        *(bf16x8*)dst = v;
    } else {
        *(bf16x8*)dst = *(const bf16x8*)((const __bf16*)a.src[k] + i);
    }
}

// ---------------------------------------------------------------------------
// Tiled GEMM: C[M,N] = (A@B + bias) * out_scale, bf16 in, fp32 acc.
// Coalesced global B rows, SW64-swizzled LDS scatter (store+read conflict-free).
// ---------------------------------------------------------------------------
__global__ __launch_bounds__(256) void gemm_bias(
    const __bf16* __restrict__ A0, const __bf16* __restrict__ A1, const __bf16* __restrict__ A2,
    const __bf16* __restrict__ B0, const __bf16* __restrict__ B1, const __bf16* __restrict__ B2,
    const __bf16* __restrict__ bias0, const __bf16* __restrict__ bias1, const __bf16* __restrict__ bias2,
    void* __restrict__ C0, void* __restrict__ C1, void* __restrict__ C2,
    int M, int N, int K, int has_bias, const int* flagp,
    float os0, float os1, float os2)
{
    const int zsel = blockIdx.z;
    const __bf16* A = (zsel == 0) ? A0 : (zsel == 1) ? A1 : A2;
    const __bf16* B = (zsel == 0) ? B0 : (zsel == 1) ? B1 : B2;
    const __bf16* bias = (zsel == 0) ? bias0 : (zsel == 1) ? bias1 : bias2;
    void* C = (zsel == 0) ? C0 : (zsel == 1) ? C1 : C2;
    const float oscale = (zsel == 0) ? os0 : (zsel == 1) ? os1 : os2;
    const int out_fp32 = flagp ? *flagp : 0;

    const int m0 = blockIdx.x * 128;
    const int n0 = blockIdx.y * 64;
    const int tid = threadIdx.x;
    const int wave = tid >> 6;
    const int ln = tid & 15;
    const int quad = (tid >> 4) & 3;

    __shared__ __bf16 As[128 * LDP];
    __shared__ __bf16 Bts[64 * 64];   // SW64-swizzled [n][k]

    floatx4 acc[2][4] = {};

    for (int k0 = 0; k0 < K; k0 += 64) {
        __syncthreads();
        for (int i = tid; i < 1024; i += 256) {
            int r = i >> 3, c8 = (i & 7) << 3;
            *(bf16x8*)&As[r * LDP + c8] = *(const bf16x8*)&A[(m0 + r) * K + k0 + c8];
        }
        for (int i = tid; i < 512; i += 256) {
            int kk = i >> 3, a8 = (i & 7) << 3;
            bf16x8 v = *(const bf16x8*)&B[(k0 + kk) * N + n0 + a8];
            #pragma unroll
            for (int j = 0; j < 8; j++) Bts[SW64(a8 + j, kk)] = v[j];
        }
        __syncthreads();
        #pragma unroll
        for (int ks = 0; ks < 2; ks++) {
            bf16x8 a[2], b[4];
            a[0] = *(const bf16x8*)&As[(wave * 32 + ln) * LDP + ks * 32 + quad * 8];
            a[1] = *(const bf16x8*)&As[(wave * 32 + 16 + ln) * LDP + ks * 32 + quad * 8];
            #pragma unroll
            for (int nt = 0; nt < 4; nt++)
                b[nt] = *(const bf16x8*)&Bts[SW64(nt * 16 + ln, ks * 32 + quad * 8)];
            #pragma unroll
            for (int rt = 0; rt < 2; rt++)
                #pragma unroll
                for (int nt = 0; nt < 4; nt++)
                    acc[rt][nt] = __builtin_amdgcn_mfma_f32_16x16x32_bf16(a[rt], b[nt], acc[rt][nt], 0, 0, 0);
        }
    }
    #pragma unroll
    for (int rt = 0; rt < 2; rt++) {
        const int row = m0 + wave * 32 + rt * 16 + quad * 4;
        #pragma unroll
        for (int nt = 0; nt < 4; nt++) {
            const int col = n0 + nt * 16 + ln;
            float bv = has_bias ? (float)bias[col] : 0.0f;
            #pragma unroll
            for (int r = 0; r < 4; r++) {
                float val = (acc[rt][nt][r] + bv) * oscale;
                if (out_fp32) ((float*)C)[(row + r) * N + col] = val;
                else ((__bf16*)C)[(row + r) * N + col] = (__bf16)val;
            }
        }
    }
}

// ---------------------------------------------------------------------------
// Flash attention r7: 40 KB LDS (4 blocks/CU) WITHOUT spilling.
// Register diet vs r6: rt-split QK+softmax (scores 32->16 regs); V prefetch
// regs removed (V(t+1) loaded+stored at iteration end, ~zero live range).
// XCD-aware grid: bh = blockIdx.x -> XCD = bh%8 -> all 16 q-tiles of a head
// share one XCD's L2; per-XCD K/V working set = 4 MB = L2 size.
// Barriers: A (loop top) publishes Ks(t)/VTs[cur]; B (after QK both rt)
// drains Ks reads so Ks(t+1) store can overlap PV.
// ---------------------------------------------------------------------------
__global__ __launch_bounds__(256, 4) void attn_kernel(
    const __bf16* __restrict__ Qg, const __bf16* __restrict__ Kg,
    const __bf16* __restrict__ Vg, __bf16* __restrict__ Og)
{
    const int bh = blockIdx.x;              // XCD = (bh + 64*q) % 8 = bh % 8
    const int b = bh >> 4, h = bh & 15;
    const int q0 = blockIdx.y * 128;
    const int base = b * 2048 * 1024 + h * 64;
    const int tid = threadIdx.x;
    const int wave = tid >> 6, ln = tid & 15, quad = (tid >> 4) & 3;

    __shared__ __bf16 Ks[64 * 64];        // 8 KB, single buffer, SW64
    __shared__ __bf16 VTs[2][64 * 64];    // 16 KB, double buffer, SW64
    __shared__ __bf16 Ps[128 * 64];       // 16 KB, PSW

    // Q fragments in registers (pre-scaled by 0.125*log2e in proj2)
    bf16x8 qf[2][2];
    #pragma unroll
    for (int rt = 0; rt < 2; rt++)
        #pragma unroll
        for (int ks = 0; ks < 2; ks++)
            qf[rt][ks] = *(const bf16x8*)&Qg[base + (q0 + wave * 32 + rt * 16 + ln) * 1024 + ks * 32 + quad * 8];

    const int kr = tid >> 3, kc = (tid & 7) << 3;  // staging map: coalesced rows

    // tile 0: load + store (published by barrier A at t=0)
    {
        bf16x8 ka = *(const bf16x8*)&Kg[base + (kr) * 1024 + kc];
        bf16x8 kb = *(const bf16x8*)&Kg[base + (kr + 32) * 1024 + kc];
        bf16x8 va = *(const bf16x8*)&Vg[base + (kr) * 1024 + kc];
        bf16x8 vb = *(const bf16x8*)&Vg[base + (kr + 32) * 1024 + kc];
        *(bf16x8*)&Ks[SW64(kr, kc)] = ka;
        *(bf16x8*)&Ks[SW64(kr + 32, kc)] = kb;
        #pragma unroll
        for (int j = 0; j < 8; j++) {
            VTs[0][SW64(kc + j, kr)] = va[j];       // row=d, col=kv
            VTs[0][SW64(kc + j, kr + 32)] = vb[j];
        }
    }

    floatx4 o_acc[2][4] = {};
    float m_i[2][4], l_i[2][4];
    #pragma unroll
    for (int rt = 0; rt < 2; rt++)
        #pragma unroll
        for (int r = 0; r < 4; r++) { m_i[rt][r] = -1e30f; l_i[rt][r] = 0.0f; }

    for (int t = 0; t < 32; t++) {
        const int cur = t & 1;
        bf16x8 nka, nkb;                    // K-only register prefetch (8 VGPRs)
        if (t < 31) {
            const int kvn = (t + 1) * 64;
            nka = *(const bf16x8*)&Kg[base + (kvn + kr) * 1024 + kc];
            nkb = *(const bf16x8*)&Kg[base + (kvn + kr + 32) * 1024 + kc];
        }
        __syncthreads();  // A: Ks(t), VTs[cur](t) visible

        // rt-split: QK then softmax per 16-row subtile (scores: 16 regs live)
        #pragma unroll
        for (int rt = 0; rt < 2; rt++) {
            floatx4 s[4] = {};
            #pragma unroll
            for (int ks = 0; ks < 2; ks++) {
                bf16x8 bb[4];
                #pragma unroll
                for (int jt = 0; jt < 4; jt++)
                    bb[jt] = *(const bf16x8*)&Ks[SW64(jt * 16 + ln, ks * 32 + quad * 8)];
                #pragma unroll
                for (int jt = 0; jt < 4; jt++)
                    s[jt] = __builtin_amdgcn_mfma_f32_16x16x32_bf16(qf[rt][ks], bb[jt], s[jt], 0, 0, 0);
            }
            #pragma unroll
            for (int r = 0; r < 4; r++) {
                float mx = fmaxf(fmaxf(s[0][r], s[1][r]), fmaxf(s[2][r], s[3][r]));
                mx = red16_max(mx);
                float m_new = fmaxf(m_i[rt][r], mx);
                const int row = wave * 32 + rt * 16 + quad * 4 + r;
                float rs = 0.0f;
                #pragma unroll
                for (int jt = 0; jt < 4; jt++) {
                    float p = fast_exp2(s[jt][r] - m_new);
                    Ps[PSW(row, jt * 16 + ln)] = (__bf16)p;
                    rs += p;
                }
                rs = red16_sum(rs);
                if (__any(mx > m_i[rt][r])) {
                    float alpha = fast_exp2(m_i[rt][r] - m_new);
                    l_i[rt][r] = l_i[rt][r] * alpha + rs;
                    #pragma unroll
                    for (int dt = 0; dt < 4; dt++) o_acc[rt][dt][r] *= alpha;
                    m_i[rt][r] = m_new;
                } else {
                    l_i[rt][r] += rs;
                }
            }
        }
        __syncthreads();  // B: all Ks reads drained

        if (t < 31) {     // overlaps PV below
            *(bf16x8*)&Ks[SW64(kr, kc)] = nka;
            *(bf16x8*)&Ks[SW64(kr + 32, kc)] = nkb;
        }

        // O += P @ V  (same-wave Ps RAW: DS in-order)
        #pragma unroll
        for (int ks = 0; ks < 2; ks++) {
            bf16x8 a[2], bb[4];
            #pragma unroll
            for (int rt = 0; rt < 2; rt++)
                a[rt] = *(const bf16x8*)&Ps[PSW(wave * 32 + rt * 16 + ln, ks * 32 + quad * 8)];
            #pragma unroll
            for (int dt = 0; dt < 4; dt++)
                bb[dt] = *(const bf16x8*)&VTs[cur][SW64(dt * 16 + ln, ks * 32 + quad * 8)];
            #pragma unroll
            for (int rt = 0; rt < 2; rt++)
                #pragma unroll
                for (int dt = 0; dt < 4; dt++)
                    o_acc[rt][dt] = __builtin_amdgcn_mfma_f32_16x16x32_bf16(a[rt], bb[dt], o_acc[rt][dt], 0, 0, 0);
        }

        // V(t+1): late load + immediate transpose-store (near-zero reg live range).
        // Reads of VTs[nxt] ended before A(t); next reads after A(t+1) -> safe.
        if (t < 31) {
            const int kvn = (t + 1) * 64;
            const int nxt = cur ^ 1;
            bf16x8 va = *(const bf16x8*)&Vg[base + (kvn + kr) * 1024 + kc];
            bf16x8 vb = *(const bf16x8*)&Vg[base + (kvn + kr + 32) * 1024 + kc];
            #pragma unroll
            for (int j = 0; j < 8; j++) {
                VTs[nxt][SW64(kc + j, kr)] = va[j];
                VTs[nxt][SW64(kc + j, kr + 32)] = vb[j];
            }
        }
    }

    #pragma unroll
    for (int rt = 0; rt < 2; rt++) {
        const int row = q0 + wave * 32 + rt * 16 + quad * 4;
        #pragma unroll
        for (int r = 0; r < 4; r++) {
            float inv = 1.0f / l_i[rt][r];
            #pragma unroll
            for (int dt = 0; dt < 4; dt++)
                Og[base + (row + r) * 1024 + dt * 16 + ln] = (__bf16)(o_acc[rt][dt][r] * inv);
        }
    }
}

// ---------------------------------------------------------------------------
extern "C" void kernel_launch(void* const* d_in, const int* in_sizes, int n_in,
                              void* d_out, int out_size, void* d_ws, size_t ws_size,
                              hipStream_t stream)
{
    int* flag = (int*)d_ws;
    __bf16* cv = (__bf16*)((char*)d_ws + 256);

    const int Z = 0, WQ = 8388608, WK = 8454144, WV = 8519680;
    const int FCQW = 8585216, FCKW = 8650752, FCVW = 8716288, FCOW = 8781824;
    const int FCQB = 9830400, FCKB = 9831424, FCVB = 9832448, FCOB = 9833472;
    __bf16* zb = cv + 10485760;
    __bf16* Qw = cv + 12582912;
    __bf16* Kw = Qw + 8388608;
    __bf16* Vw = Kw + 8388608;
    __bf16* Ow = cv + Z;  // reuse z-copy region (dead after proj1)

    detect_dtype<<<1, 256, 0, stream>>>((const unsigned short*)d_in[0], flag);

    ConvArgs ca;
    const int offs[12] = {Z, WQ, WK, WV, FCQW, FCQB, FCKW, FCKB, FCVW, FCVB, FCOW, FCOB};
    for (int i = 0; i < 12; i++) { ca.src[i] = d_in[i]; ca.n[i] = in_sizes[i]; ca.off[i] = offs[i]; }
    convert_inputs<<<dim3(4096, 1), 256, 0, stream>>>(ca, cv, flag, 0);
    convert_inputs<<<dim3(512, 11), 256, 0, stream>>>(ca, cv, flag, 1);

    gemm_bias<<<dim3(64, 1, 3), 256, 0, stream>>>(
        cv + Z, cv + Z, cv + Z, cv + WQ, cv + WK, cv + WV,
        cv + FCQB, cv + FCQB, cv + FCQB,
        zb, zb + 524288, zb + 1048576, 8192, 64, 1024, 0, nullptr,
        1.0f, 1.0f, 1.0f);

    const float QSC = 0.125f * 1.44269504088896f;  // fold 1/sqrt(dk) * log2(e) into Q
    gemm_bias<<<dim3(64, 16, 3), 256, 0, stream>>>(
        zb, zb + 524288, zb + 1048576,
        cv + FCQW, cv + FCKW, cv + FCVW, cv + FCQB, cv + FCKB, cv + FCVB,
        Qw, Kw, Vw, 8192, 1024, 64, 1, nullptr,
        QSC, 1.0f, 1.0f);

    attn_kernel<<<dim3(64, 16), 256, 0, stream>>>(Qw, Kw, Vw, Ow);

    gemm_bias<<<dim3(64, 16, 1), 256, 0, stream>>>(
        Ow, Ow, Ow, cv + FCOW, cv + FCOW, cv + FCOW, cv + FCOB, cv + FCOB, cv + FCOB,
        d_out, d_out, d_out, 8192, 1024, 1024, 1, flag,
        1.0f, 1.0f, 1.0f);
}

// Round 8
// 348.708 us; speedup vs baseline: 2.3953x; 2.3953x over previous
//
#include <hip/hip_runtime.h>

// multi_SelfAttention on MI355X (gfx950). Inputs fp32 (runtime-detected);
// bf16 MFMA compute; output dtype per flag.
// convert -> proj1 -> proj2 (Q pre-scaled 0.125*log2e) -> flash attn -> proj3.
// r8: attention computes S^T = mfma(K, Q) so P exits in a layout writable with
// b64 vector stores (kills the scalar-b16-store bank cost), per-lane softmax
// state, and __launch_bounds__(256,3) (r6/r7's (256,4) spilled ~1.3 GB/launch).

typedef __bf16 bf16x8 __attribute__((ext_vector_type(8)));
typedef __bf16 bf16x4 __attribute__((ext_vector_type(4)));
typedef float floatx4 __attribute__((ext_vector_type(4)));

#define LDP 72  // padded stride for GEMM A tiles only

// 64-stride tile swizzle: 16B-chunk XOR; conflict-minimal for row-major b128
// reads (row=..+ln), b64 P stores, and transpose-scatter b16 stores.
#define SW64(row, col) (((row) << 6) | (((((col) >> 3) ^ ((row) & 7) ^ (((row) >> 3) & 7)) << 3) | ((col) & 7)))

#if __has_builtin(__builtin_amdgcn_exp2f)
__device__ __forceinline__ float fast_exp2(float x) { return __builtin_amdgcn_exp2f(x); }
#else
__device__ __forceinline__ float fast_exp2(float x) { return exp2f(x); }
#endif

// ---------------------------------------------------------------------------
__global__ void detect_dtype(const unsigned short* __restrict__ z, int* __restrict__ flag) {
    __shared__ int cnt;
    if (threadIdx.x == 0) cnt = 0;
    __syncthreads();
    int local = 0;
    for (int i = threadIdx.x; i < 16384; i += 256) {
        unsigned int u = (unsigned int)z[i] << 16;
        float x = __uint_as_float(u);
        float ax = fabsf(x);
        if (!(ax <= 1024.0f) || (x != 0.0f && ax < 1e-20f)) local++;
    }
    atomicAdd(&cnt, local);
    __syncthreads();
    if (threadIdx.x == 0) *flag = (cnt > 1310) ? 1 : 0;
}

// ---------------------------------------------------------------------------
struct ConvArgs { const void* src[12]; int n[12]; int off[12]; };

__global__ void convert_inputs(ConvArgs a, __bf16* __restrict__ cv, const int* __restrict__ flag,
                               int base_k) {
    const int k = blockIdx.y + base_k;
    const int i = (blockIdx.x * 256 + threadIdx.x) * 8;
    if (i >= a.n[k]) return;
    __bf16* dst = cv + a.off[k] + i;
    if (*flag) {
        const float* s = (const float*)a.src[k] + i;
        float4 f0 = *(const float4*)s;
        float4 f1 = *(const float4*)(s + 4);
        bf16x8 v;
        v[0] = (__bf16)f0.x; v[1] = (__bf16)f0.y; v[2] = (__bf16)f0.z; v[3] = (__bf16)f0.w;
        v[4] = (__bf16)f1.x; v[5] = (__bf16)f1.y; v[6] = (__bf16)f1.z; v[7] = (__bf16)f1.w;
        *(bf16x8*)dst = v;
    } else {
        *(bf16x8*)dst = *(const bf16x8*)((const __bf16*)a.src[k] + i);
    }
}

// ---------------------------------------------------------------------------
// Tiled GEMM: C[M,N] = (A@B + bias) * out_scale, bf16 in, fp32 acc.
// ---------------------------------------------------------------------------
__global__ __launch_bounds__(256) void gemm_bias(
    const __bf16* __restrict__ A0, const __bf16* __restrict__ A1, const __bf16* __restrict__ A2,
    const __bf16* __restrict__ B0, const __bf16* __restrict__ B1, const __bf16* __restrict__ B2,
    const __bf16* __restrict__ bias0, const __bf16* __restrict__ bias1, const __bf16* __restrict__ bias2,
    void* __restrict__ C0, void* __restrict__ C1, void* __restrict__ C2,
    int M, int N, int K, int has_bias, const int* flagp,
    float os0, float os1, float os2)
{
    const int zsel = blockIdx.z;
    const __bf16* A = (zsel == 0) ? A0 : (zsel == 1) ? A1 : A2;
    const __bf16* B = (zsel == 0) ? B0 : (zsel == 1) ? B1 : B2;
    const __bf16* bias = (zsel == 0) ? bias0 : (zsel == 1) ? bias1 : bias2;
    void* C = (zsel == 0) ? C0 : (zsel == 1) ? C1 : C2;
    const float oscale = (zsel == 0) ? os0 : (zsel == 1) ? os1 : os2;
    const int out_fp32 = flagp ? *flagp : 0;

    const int m0 = blockIdx.x * 128;
    const int n0 = blockIdx.y * 64;
    const int tid = threadIdx.x;
    const int wave = tid >> 6;
    const int ln = tid & 15;
    const int quad = (tid >> 4) & 3;

    __shared__ __bf16 As[128 * LDP];
    __shared__ __bf16 Bts[64 * 64];   // SW64-swizzled [n][k]

    floatx4 acc[2][4] = {};

    for (int k0 = 0; k0 < K; k0 += 64) {
        __syncthreads();
        for (int i = tid; i < 1024; i += 256) {
            int r = i >> 3, c8 = (i & 7) << 3;
            *(bf16x8*)&As[r * LDP + c8] = *(const bf16x8*)&A[(m0 + r) * K + k0 + c8];
        }
        for (int i = tid; i < 512; i += 256) {
            int kk = i >> 3, a8 = (i & 7) << 3;
            bf16x8 v = *(const bf16x8*)&B[(k0 + kk) * N + n0 + a8];
            #pragma unroll
            for (int j = 0; j < 8; j++) Bts[SW64(a8 + j, kk)] = v[j];
        }
        __syncthreads();
        #pragma unroll
        for (int ks = 0; ks < 2; ks++) {
            bf16x8 a[2], b[4];
            a[0] = *(const bf16x8*)&As[(wave * 32 + ln) * LDP + ks * 32 + quad * 8];
            a[1] = *(const bf16x8*)&As[(wave * 32 + 16 + ln) * LDP + ks * 32 + quad * 8];
            #pragma unroll
            for (int nt = 0; nt < 4; nt++)
                b[nt] = *(const bf16x8*)&Bts[SW64(nt * 16 + ln, ks * 32 + quad * 8)];
            #pragma unroll
            for (int rt = 0; rt < 2; rt++)
                #pragma unroll
                for (int nt = 0; nt < 4; nt++)
                    acc[rt][nt] = __builtin_amdgcn_mfma_f32_16x16x32_bf16(a[rt], b[nt], acc[rt][nt], 0, 0, 0);
        }
    }
    #pragma unroll
    for (int rt = 0; rt < 2; rt++) {
        const int row = m0 + wave * 32 + rt * 16 + quad * 4;
        #pragma unroll
        for (int nt = 0; nt < 4; nt++) {
            const int col = n0 + nt * 16 + ln;
            float bv = has_bias ? (float)bias[col] : 0.0f;
            #pragma unroll
            for (int r = 0; r < 4; r++) {
                float val = (acc[rt][nt][r] + bv) * oscale;
                if (out_fp32) ((float*)C)[(row + r) * N + col] = val;
                else ((__bf16*)C)[(row + r) * N + col] = (__bf16)val;
            }
        }
    }
}

// ---------------------------------------------------------------------------
// Flash attention r8 (S^T formulation):
//  S^T[j][q] = mfma(A=K-frag, B=Q-frag) -> lane holds j=quad*4+r, q=ln&15.
//  Softmax state (m,l) is per-lane scalar (q=ln&15); full-j reduce = own-16
//  + shfl_xor(16,32). P packed as bf16x4 along j -> b64 stores into Ps[q][j]
//  (8 b64 vs 32 b16 per thread/tile). PV: A=Ps rows (contiguous b128),
//  B=VTs[d][j] rows as before; O lands in the usual C-layout.
//  LDS 40 KB; __launch_bounds__(256,3): 170-reg cap, NO spill (r6/r7 lesson).
//  XCD grid: bh=blockIdx.x -> XCD=bh%8 -> per-XCD K/V set ~4MB = L2.
// ---------------------------------------------------------------------------
__global__ __launch_bounds__(256, 3) void attn_kernel(
    const __bf16* __restrict__ Qg, const __bf16* __restrict__ Kg,
    const __bf16* __restrict__ Vg, __bf16* __restrict__ Og)
{
    const int bh = blockIdx.x;              // XCD = (bh + 64*q) % 8 = bh % 8
    const int b = bh >> 4, h = bh & 15;
    const int q0 = blockIdx.y * 128;
    const int base = b * 2048 * 1024 + h * 64;
    const int tid = threadIdx.x;
    const int wave = tid >> 6, ln = tid & 63;
    const int lnq = tid & 15, quad = (tid >> 4) & 3;

    __shared__ __bf16 Ks[64 * 64];        // 8 KB, single buffer, SW64 [j][k]
    __shared__ __bf16 VTs[2][64 * 64];    // 16 KB, double buffer, SW64 [d][j]
    __shared__ __bf16 Ps[128 * 64];       // 16 KB, SW64 [q][j]

    // Q fragments (B-operand of S^T): lane q=lnq, k=quad*8 (pre-scaled in proj2)
    bf16x8 qf[2][2];
    #pragma unroll
    for (int rt = 0; rt < 2; rt++)
        #pragma unroll
        for (int ks = 0; ks < 2; ks++)
            qf[rt][ks] = *(const bf16x8*)&Qg[base + (q0 + wave * 32 + rt * 16 + lnq) * 1024 + ks * 32 + quad * 8];

    const int kr = tid >> 3, kc = (tid & 7) << 3;  // staging map: coalesced rows

    {   // tile 0 (published by barrier A at t=0)
        bf16x8 ka = *(const bf16x8*)&Kg[base + (kr) * 1024 + kc];
        bf16x8 kb = *(const bf16x8*)&Kg[base + (kr + 32) * 1024 + kc];
        bf16x8 va = *(const bf16x8*)&Vg[base + (kr) * 1024 + kc];
        bf16x8 vb = *(const bf16x8*)&Vg[base + (kr + 32) * 1024 + kc];
        *(bf16x8*)&Ks[SW64(kr, kc)] = ka;
        *(bf16x8*)&Ks[SW64(kr + 32, kc)] = kb;
        #pragma unroll
        for (int j = 0; j < 8; j++) {
            VTs[0][SW64(kc + j, kr)] = va[j];
            VTs[0][SW64(kc + j, kr + 32)] = vb[j];
        }
    }

    floatx4 o_acc[2][4] = {};
    float m_i[2] = {-1e30f, -1e30f}, l_i[2] = {0.0f, 0.0f};

    for (int t = 0; t < 32; t++) {
        const int cur = t & 1;
        bf16x8 nka, nkb;                    // K register prefetch (8 VGPRs)
        if (t < 31) {
            const int kvn = (t + 1) * 64;
            nka = *(const bf16x8*)&Kg[base + (kvn + kr) * 1024 + kc];
            nkb = *(const bf16x8*)&Kg[base + (kvn + kr + 32) * 1024 + kc];
        }
        __syncthreads();  // A: Ks(t), VTs[cur](t) visible

        #pragma unroll
        for (int rt = 0; rt < 2; rt++) {
            // S^T: lane holds j = jt*16+quad*4+r (16 values), q = lnq
            floatx4 s[4] = {};
            #pragma unroll
            for (int ks = 0; ks < 2; ks++) {
                bf16x8 ak[4];
                #pragma unroll
                for (int jt = 0; jt < 4; jt++)
                    ak[jt] = *(const bf16x8*)&Ks[SW64(jt * 16 + lnq, ks * 32 + quad * 8)];
                #pragma unroll
                for (int jt = 0; jt < 4; jt++)
                    s[jt] = __builtin_amdgcn_mfma_f32_16x16x32_bf16(ak[jt], qf[rt][ks], s[jt], 0, 0, 0);
            }
            // softmax for q=lnq: own-16 max + cross-quad shfl
            float mx = s[0][0];
            #pragma unroll
            for (int jt = 0; jt < 4; jt++)
                #pragma unroll
                for (int r = 0; r < 4; r++) mx = fmaxf(mx, s[jt][r]);
            mx = fmaxf(mx, __shfl_xor(mx, 16));
            mx = fmaxf(mx, __shfl_xor(mx, 32));
            float m_new = fmaxf(m_i[rt], mx);
            float rs = 0.0f;
            #pragma unroll
            for (int jt = 0; jt < 4; jt++) {
                bf16x4 pk;
                #pragma unroll
                for (int r = 0; r < 4; r++) {
                    float p = fast_exp2(s[jt][r] - m_new);
                    rs += p;
                    pk[r] = (__bf16)p;
                }
                *(bf16x4*)&Ps[SW64(wave * 32 + rt * 16 + lnq, jt * 16 + quad * 4)] = pk;
            }
            rs += __shfl_xor(rs, 16);
            rs += __shfl_xor(rs, 32);
            if (__any(mx > m_i[rt])) {
                float alpha = fast_exp2(m_i[rt] - m_new);
                l_i[rt] = l_i[rt] * alpha + rs;
                m_i[rt] = m_new;
                #pragma unroll
                for (int r = 0; r < 4; r++) {
                    float ar = __shfl(alpha, (ln & 48) | (quad * 4 + r));
                    #pragma unroll
                    for (int dt = 0; dt < 4; dt++) o_acc[rt][dt][r] *= ar;
                }
            } else {
                l_i[rt] += rs;
            }
        }
        __syncthreads();  // B: all Ks reads drained

        if (t < 31) {     // overlaps PV below
            *(bf16x8*)&Ks[SW64(kr, kc)] = nka;
            *(bf16x8*)&Ks[SW64(kr + 32, kc)] = nkb;
        }

        // O += P @ V  (A=Ps rows b128 — same-wave RAW, DS in-order; B=VTs rows)
        #pragma unroll
        for (int ks = 0; ks < 2; ks++) {
            bf16x8 ap[2], bv[4];
            #pragma unroll
            for (int rt = 0; rt < 2; rt++)
                ap[rt] = *(const bf16x8*)&Ps[SW64(wave * 32 + rt * 16 + lnq, ks * 32 + quad * 8)];
            #pragma unroll
            for (int dt = 0; dt < 4; dt++)
                bv[dt] = *(const bf16x8*)&VTs[cur][SW64(dt * 16 + lnq, ks * 32 + quad * 8)];
            #pragma unroll
            for (int rt = 0; rt < 2; rt++)
                #pragma unroll
                for (int dt = 0; dt < 4; dt++)
                    o_acc[rt][dt] = __builtin_amdgcn_mfma_f32_16x16x32_bf16(ap[rt], bv[dt], o_acc[rt][dt], 0, 0, 0);
        }

        // V(t+1): late load + transpose store (short reg live range).
        if (t < 31) {
            const int kvn = (t + 1) * 64;
            const int nxt = cur ^ 1;
            bf16x8 va = *(const bf16x8*)&Vg[base + (kvn + kr) * 1024 + kc];
            bf16x8 vb = *(const bf16x8*)&Vg[base + (kvn + kr + 32) * 1024 + kc];
            #pragma unroll
            for (int j = 0; j < 8; j++) {
                VTs[nxt][SW64(kc + j, kr)] = va[j];
                VTs[nxt][SW64(kc + j, kr + 32)] = vb[j];
            }
        }
    }

    #pragma unroll
    for (int rt = 0; rt < 2; rt++) {
        float inv = 1.0f / l_i[rt];         // valid at q=lnq
        #pragma unroll
        for (int r = 0; r < 4; r++) {
            float ir = __shfl(inv, (ln & 48) | (quad * 4 + r));
            const int row = q0 + wave * 32 + rt * 16 + quad * 4 + r;
            #pragma unroll
            for (int dt = 0; dt < 4; dt++)
                Og[base + row * 1024 + dt * 16 + lnq] = (__bf16)(o_acc[rt][dt][r] * ir);
        }
    }
}

// ---------------------------------------------------------------------------
extern "C" void kernel_launch(void* const* d_in, const int* in_sizes, int n_in,
                              void* d_out, int out_size, void* d_ws, size_t ws_size,
                              hipStream_t stream)
{
    int* flag = (int*)d_ws;
    __bf16* cv = (__bf16*)((char*)d_ws + 256);

    const int Z = 0, WQ = 8388608, WK = 8454144, WV = 8519680;
    const int FCQW = 8585216, FCKW = 8650752, FCVW = 8716288, FCOW = 8781824;
    const int FCQB = 9830400, FCKB = 9831424, FCVB = 9832448, FCOB = 9833472;
    __bf16* zb = cv + 10485760;
    __bf16* Qw = cv + 12582912;
    __bf16* Kw = Qw + 8388608;
    __bf16* Vw = Kw + 8388608;
    __bf16* Ow = cv + Z;  // reuse z-copy region (dead after proj1)

    detect_dtype<<<1, 256, 0, stream>>>((const unsigned short*)d_in[0], flag);

    ConvArgs ca;
    const int offs[12] = {Z, WQ, WK, WV, FCQW, FCQB, FCKW, FCKB, FCVW, FCVB, FCOW, FCOB};
    for (int i = 0; i < 12; i++) { ca.src[i] = d_in[i]; ca.n[i] = in_sizes[i]; ca.off[i] = offs[i]; }
    convert_inputs<<<dim3(4096, 1), 256, 0, stream>>>(ca, cv, flag, 0);
    convert_inputs<<<dim3(512, 11), 256, 0, stream>>>(ca, cv, flag, 1);

    gemm_bias<<<dim3(64, 1, 3), 256, 0, stream>>>(
        cv + Z, cv + Z, cv + Z, cv + WQ, cv + WK, cv + WV,
        cv + FCQB, cv + FCQB, cv + FCQB,
        zb, zb + 524288, zb + 1048576, 8192, 64, 1024, 0, nullptr,
        1.0f, 1.0f, 1.0f);

    const float QSC = 0.125f * 1.44269504088896f;  // fold 1/sqrt(dk) * log2(e) into Q
    gemm_bias<<<dim3(64, 16, 3), 256, 0, stream>>>(
        zb, zb + 524288, zb + 1048576,
        cv + FCQW, cv + FCKW, cv + FCVW, cv + FCQB, cv + FCKB, cv + FCVB,
        Qw, Kw, Vw, 8192, 1024, 64, 1, nullptr,
        QSC, 1.0f, 1.0f);

    attn_kernel<<<dim3(64, 16), 256, 0, stream>>>(Qw, Kw, Vw, Ow);

    gemm_bias<<<dim3(64, 16, 1), 256, 0, stream>>>(
        Ow, Ow, Ow, cv + FCOW, cv + FCOW, cv + FCOW, cv + FCOB, cv + FCOB, cv + FCOB,
        d_out, d_out, d_out, 8192, 1024, 1024, 1, flag,
        1.0f, 1.0f, 1.0f);
}